// Round 1
// baseline (819.869 us; speedup 1.0000x reference)
//
#include <hip/hip_runtime.h>
#include <math.h>

#define Bn 4
#define Vn 5
#define Cc 32
#define Hh 256
#define Ww 320
#define DD 4
#define GG 8
#define HW (Hh*Ww)

// ---------------------------------------------------------------------------
// Prologue: per (b, src_view i=1..4) compute P = src_proj_new @ inv(ref_proj_new)
// proj_new(p) = [ K[:3,:3] @ E[:3,:4] ; 0 0 0 1 ].  Double-precision Gauss-Jordan
// 4x4 inverse (16 matrices total -- negligible cost, high accuracy).
// Output: 12 floats per (b,i): rot row-major [0..8], trans [9..11].
// ---------------------------------------------------------------------------
__global__ void proj_kernel(const float* __restrict__ proj, float* __restrict__ out12) {
    int t = blockIdx.x * blockDim.x + threadIdx.x;
    if (t >= Bn * (Vn - 1)) return;
    int b = t / (Vn - 1);
    int i = t % (Vn - 1) + 1;

    const float* pb = proj + (size_t)b * Vn * 2 * 16;

    double refm[16], srcm[16];
    // ref_proj_new (v = 0)
    {
        const float* E = pb + 0 * 32 + 0;
        const float* K = pb + 0 * 32 + 16;
        for (int r = 0; r < 3; r++)
            for (int c = 0; c < 4; c++) {
                double s = 0.0;
                for (int k = 0; k < 3; k++) s += (double)K[r*4+k] * (double)E[k*4+c];
                refm[r*4+c] = s;
            }
        for (int c = 0; c < 4; c++) refm[12+c] = (double)E[12+c];
    }
    // src_proj_new (v = i)
    {
        const float* E = pb + i * 32 + 0;
        const float* K = pb + i * 32 + 16;
        for (int r = 0; r < 3; r++)
            for (int c = 0; c < 4; c++) {
                double s = 0.0;
                for (int k = 0; k < 3; k++) s += (double)K[r*4+k] * (double)E[k*4+c];
                srcm[r*4+c] = s;
            }
        for (int c = 0; c < 4; c++) srcm[12+c] = (double)E[12+c];
    }

    // invert refm via Gauss-Jordan with partial pivoting
    double a[16], inv[16];
    for (int k = 0; k < 16; k++) { a[k] = refm[k]; inv[k] = 0.0; }
    inv[0] = inv[5] = inv[10] = inv[15] = 1.0;
    for (int col = 0; col < 4; col++) {
        int piv = col; double best = fabs(a[col*4+col]);
        for (int r = col + 1; r < 4; r++) {
            double v = fabs(a[r*4+col]);
            if (v > best) { best = v; piv = r; }
        }
        if (piv != col) {
            for (int c = 0; c < 4; c++) {
                double tmp = a[col*4+c]; a[col*4+c] = a[piv*4+c]; a[piv*4+c] = tmp;
                tmp = inv[col*4+c]; inv[col*4+c] = inv[piv*4+c]; inv[piv*4+c] = tmp;
            }
        }
        double rd = 1.0 / a[col*4+col];
        for (int c = 0; c < 4; c++) { a[col*4+c] *= rd; inv[col*4+c] *= rd; }
        for (int r = 0; r < 4; r++) {
            if (r == col) continue;
            double f = a[r*4+col];
            for (int c = 0; c < 4; c++) { a[r*4+c] -= f * a[col*4+c]; inv[r*4+c] -= f * inv[col*4+c]; }
        }
    }

    // P = srcm @ inv(refm)
    double P[16];
    for (int r = 0; r < 4; r++)
        for (int c = 0; c < 4; c++) {
            double s = 0.0;
            for (int k = 0; k < 4; k++) s += srcm[r*4+k] * inv[k*4+c];
            P[r*4+c] = s;
        }

    float* o = out12 + t * 12;
    o[0] = (float)P[0];  o[1] = (float)P[1];  o[2]  = (float)P[2];
    o[3] = (float)P[4];  o[4] = (float)P[5];  o[5]  = (float)P[6];
    o[6] = (float)P[8];  o[7] = (float)P[9];  o[8]  = (float)P[10];
    o[9] = (float)P[3];  o[10] = (float)P[7]; o[11] = (float)P[11];
}

// ---------------------------------------------------------------------------
// Main kernel: one thread per (b,h,w) pixel.
// ref[32] and acc[g*4+d] held in VGPRs (c,d loops fully unrolled so indices
// are compile-time constant -- no scratch spill).
// ---------------------------------------------------------------------------
__global__ __launch_bounds__(256) void cost_kernel(
    const float* __restrict__ depth_values,
    const float* __restrict__ features,
    const float* __restrict__ depth_interval,
    const float* __restrict__ view_weights,
    const float* __restrict__ P12,
    float* __restrict__ sim_out,
    float* __restrict__ samp_out)
{
    int idx = blockIdx.x * 256 + threadIdx.x;
    int b   = idx / HW;
    int pix = idx - b * HW;
    int h   = pix / Ww;
    int w   = pix - h * Ww;

    float inv_d = 1.0f / depth_values[b * HW + pix];
    float itv   = depth_interval[b * HW + pix];
    float dmin  = inv_d - 2.0f * itv;
    float dmax  = inv_d + 2.0f * itv;
    float step  = (dmax - dmin) / 3.0f;

    float depth[DD];
    #pragma unroll
    for (int d = 0; d < DD; d++) {
        float s  = dmin + (float)d * step;
        depth[d] = 1.0f / s;
        samp_out[((size_t)b * DD + d) * HW + pix] = depth[d];
    }

    // ref features (view 0), 32 channels
    float ref[Cc];
    const float* refp = features + (size_t)b * Vn * Cc * HW + pix;
    #pragma unroll
    for (int c = 0; c < Cc; c++) ref[c] = refp[(size_t)c * HW];

    float acc[GG * DD];
    #pragma unroll
    for (int k = 0; k < GG * DD; k++) acc[k] = 0.0f;
    float wsum = 0.0f;

    const float xf = (float)w, yf = (float)h;

    for (int i = 0; i < Vn - 1; i++) {
        const float* P = P12 + (b * (Vn - 1) + i) * 12;
        float rx = P[0] * xf + P[1] * yf + P[2];
        float ry = P[3] * xf + P[4] * yf + P[5];
        float rz = P[6] * xf + P[7] * yf + P[8];
        float tx = P[9], ty = P[10], tz = P[11];

        float vw = view_weights[((size_t)b * (Vn - 1) + i) * HW + pix];
        wsum += vw;
        float scale = 0.25f * vw;   // fold mean(2) over Cc/G=4 and view weight

        const float* src = features + ((size_t)(b * Vn) + (i + 1)) * Cc * HW;

        #pragma unroll
        for (int d = 0; d < DD; d++) {
            float D  = depth[d];
            float px = rx * D + tx;
            float py = ry * D + ty;
            float pz = rz * D + tz;
            float rpz = 1.0f / pz;
            float gx = px * rpz;
            float gy = py * rpz;

            float x0f = floorf(gx);
            float y0f = floorf(gy);
            float wx1 = gx - x0f;
            float wy1 = gy - y0f;
            float wx0 = 1.0f - wx1;
            float wy0 = 1.0f - wy1;

            bool vx0 = (x0f        >= 0.0f) && (x0f        <= (float)(Ww - 1));
            bool vx1 = (x0f + 1.0f >= 0.0f) && (x0f + 1.0f <= (float)(Ww - 1));
            bool vy0 = (y0f        >= 0.0f) && (y0f        <= (float)(Hh - 1));
            bool vy1 = (y0f + 1.0f >= 0.0f) && (y0f + 1.0f <= (float)(Hh - 1));

            int xc0 = (int)fminf(fmaxf(x0f,        0.0f), (float)(Ww - 1));
            int xc1 = (int)fminf(fmaxf(x0f + 1.0f, 0.0f), (float)(Ww - 1));
            int yc0 = (int)fminf(fmaxf(y0f,        0.0f), (float)(Hh - 1));
            int yc1 = (int)fminf(fmaxf(y0f + 1.0f, 0.0f), (float)(Hh - 1));

            float W00 = (vx0 && vy0) ? wx0 * wy0 * scale : 0.0f;
            float W10 = (vx1 && vy0) ? wx1 * wy0 * scale : 0.0f;
            float W01 = (vx0 && vy1) ? wx0 * wy1 * scale : 0.0f;
            float W11 = (vx1 && vy1) ? wx1 * wy1 * scale : 0.0f;

            int o00 = yc0 * Ww + xc0;
            int o10 = yc0 * Ww + xc1;
            int o01 = yc1 * Ww + xc0;
            int o11 = yc1 * Ww + xc1;

            #pragma unroll
            for (int c = 0; c < Cc; c++) {
                const float* p = src + (size_t)c * HW;
                float val = W00 * p[o00] + W10 * p[o10] + W01 * p[o01] + W11 * p[o11];
                acc[(c >> 2) * DD + d] += val * ref[c];
            }
        }
    }

    float dn = 1.0f / (wsum + 1e-6f);
    float* so = sim_out + (size_t)b * (GG * DD) * HW + pix;
    #pragma unroll
    for (int k = 0; k < GG * DD; k++) so[(size_t)k * HW] = acc[k] * dn;
}

extern "C" void kernel_launch(void* const* d_in, const int* in_sizes, int n_in,
                              void* d_out, int out_size, void* d_ws, size_t ws_size,
                              hipStream_t stream) {
    const float* depth_values   = (const float*)d_in[0];
    const float* features       = (const float*)d_in[1];
    const float* projm          = (const float*)d_in[2];
    const float* depth_interval = (const float*)d_in[3];
    const float* view_weights   = (const float*)d_in[6];

    float* out      = (float*)d_out;
    float* sim_out  = out;                              // (B, G*DD, H, W)
    float* samp_out = out + (size_t)Bn * GG * DD * HW;  // (B, DD, H, W)
    float* P12      = (float*)d_ws;                     // 16 x 12 floats

    proj_kernel<<<1, 64, 0, stream>>>(projm, P12);
    cost_kernel<<<(Bn * HW) / 256, 256, 0, stream>>>(
        depth_values, features, depth_interval, view_weights, P12, sim_out, samp_out);
}

// Round 2
// 685.748 us; speedup vs baseline: 1.1956x; 1.1956x over previous
//
#include <hip/hip_runtime.h>
#include <math.h>

#define Bn 4
#define Vn 5
#define Cc 32
#define Hh 256
#define Ww 320
#define DD 4
#define GG 8
#define HW (Hh*Ww)

// ---------------------------------------------------------------------------
// Prologue: per (b, src_view i=1..4) compute P = src_proj_new @ inv(ref_proj_new)
// ---------------------------------------------------------------------------
__global__ void proj_kernel(const float* __restrict__ proj, float* __restrict__ out12) {
    int t = blockIdx.x * blockDim.x + threadIdx.x;
    if (t >= Bn * (Vn - 1)) return;
    int b = t / (Vn - 1);
    int i = t % (Vn - 1) + 1;

    const float* pb = proj + (size_t)b * Vn * 2 * 16;

    double refm[16], srcm[16];
    {
        const float* E = pb + 0 * 32 + 0;
        const float* K = pb + 0 * 32 + 16;
        for (int r = 0; r < 3; r++)
            for (int c = 0; c < 4; c++) {
                double s = 0.0;
                for (int k = 0; k < 3; k++) s += (double)K[r*4+k] * (double)E[k*4+c];
                refm[r*4+c] = s;
            }
        for (int c = 0; c < 4; c++) refm[12+c] = (double)E[12+c];
    }
    {
        const float* E = pb + i * 32 + 0;
        const float* K = pb + i * 32 + 16;
        for (int r = 0; r < 3; r++)
            for (int c = 0; c < 4; c++) {
                double s = 0.0;
                for (int k = 0; k < 3; k++) s += (double)K[r*4+k] * (double)E[k*4+c];
                srcm[r*4+c] = s;
            }
        for (int c = 0; c < 4; c++) srcm[12+c] = (double)E[12+c];
    }

    double a[16], inv[16];
    for (int k = 0; k < 16; k++) { a[k] = refm[k]; inv[k] = 0.0; }
    inv[0] = inv[5] = inv[10] = inv[15] = 1.0;
    for (int col = 0; col < 4; col++) {
        int piv = col; double best = fabs(a[col*4+col]);
        for (int r = col + 1; r < 4; r++) {
            double v = fabs(a[r*4+col]);
            if (v > best) { best = v; piv = r; }
        }
        if (piv != col) {
            for (int c = 0; c < 4; c++) {
                double tmp = a[col*4+c]; a[col*4+c] = a[piv*4+c]; a[piv*4+c] = tmp;
                tmp = inv[col*4+c]; inv[col*4+c] = inv[piv*4+c]; inv[piv*4+c] = tmp;
            }
        }
        double rd = 1.0 / a[col*4+col];
        for (int c = 0; c < 4; c++) { a[col*4+c] *= rd; inv[col*4+c] *= rd; }
        for (int r = 0; r < 4; r++) {
            if (r == col) continue;
            double f = a[r*4+col];
            for (int c = 0; c < 4; c++) { a[r*4+c] -= f * a[col*4+c]; inv[r*4+c] -= f * inv[col*4+c]; }
        }
    }

    double P[16];
    for (int r = 0; r < 4; r++)
        for (int c = 0; c < 4; c++) {
            double s = 0.0;
            for (int k = 0; k < 4; k++) s += srcm[r*4+k] * inv[k*4+c];
            P[r*4+c] = s;
        }

    float* o = out12 + t * 12;
    o[0] = (float)P[0];  o[1] = (float)P[1];  o[2]  = (float)P[2];
    o[3] = (float)P[4];  o[4] = (float)P[5];  o[5]  = (float)P[6];
    o[6] = (float)P[8];  o[7] = (float)P[9];  o[8]  = (float)P[10];
    o[9] = (float)P[3];  o[10] = (float)P[7]; o[11] = (float)P[11];
}

// ---------------------------------------------------------------------------
// Main kernel: one thread per (b,h,w).
// Key ideas vs round 1:
//  * __launch_bounds__(256,4): cap VGPR at 128 -> 4 waves/SIMD resident.
//  * One base address per (c,d); the 4 bilinear corners are immediate-offset
//    loads (+4B, +1280B, +1284B). Border handled by remapping the two per-axis
//    sample weights onto a patch whose origin is clamped to [0,318]x[0,254]:
//      dx = x0 - clamp(x0,0,W-2):
//        dx==0  -> interior: (w0, w1)
//        dx==-1 -> only x1=0 contributes, lands on patch col0: (w1, 0)
//        dx==1  -> only x0=W-1 contributes, lands on patch col1: (0, w0)
//        else   -> (0,0)
//    Computed once per (view, depth), not per channel.
//  * Max base offset = 254*320+318 -> +1284B stays inside the last feature
//    plane (element 81919), so no OOB even for the final plane.
// ---------------------------------------------------------------------------
__global__ __launch_bounds__(256, 4) void cost_kernel(
    const float* __restrict__ depth_values,
    const float* __restrict__ features,
    const float* __restrict__ depth_interval,
    const float* __restrict__ view_weights,
    const float* __restrict__ P12,
    float* __restrict__ sim_out,
    float* __restrict__ samp_out)
{
    int idx = blockIdx.x * 256 + threadIdx.x;
    int b   = idx / HW;
    int pix = idx - b * HW;
    int h   = pix / Ww;
    int w   = pix - h * Ww;

    float inv_d = 1.0f / depth_values[b * HW + pix];
    float itv   = depth_interval[b * HW + pix];
    float dmin  = inv_d - 2.0f * itv;
    float dmax  = inv_d + 2.0f * itv;
    float step  = (dmax - dmin) / 3.0f;

    float depth[DD];
    #pragma unroll
    for (int d = 0; d < DD; d++) {
        float s  = dmin + (float)d * step;
        depth[d] = 1.0f / s;
        samp_out[((size_t)b * DD + d) * HW + pix] = depth[d];
    }

    float ref[Cc];
    const float* refp = features + (size_t)b * Vn * Cc * HW + pix;
    #pragma unroll
    for (int c = 0; c < Cc; c++) ref[c] = refp[(size_t)c * HW];

    float acc[GG * DD];
    #pragma unroll
    for (int k = 0; k < GG * DD; k++) acc[k] = 0.0f;
    float wsum = 0.0f;

    const float xf = (float)w, yf = (float)h;

    for (int i = 0; i < Vn - 1; i++) {
        const float* P = P12 + (b * (Vn - 1) + i) * 12;
        float rx = P[0] * xf + P[1] * yf + P[2];
        float ry = P[3] * xf + P[4] * yf + P[5];
        float rz = P[6] * xf + P[7] * yf + P[8];
        float tx = P[9], ty = P[10], tz = P[11];

        float vw = view_weights[((size_t)b * (Vn - 1) + i) * HW + pix];
        wsum += vw;
        float scale = 0.25f * vw;   // fold mean over Cc/G=4 and view weight

        const float* src = features + ((size_t)(b * Vn) + (i + 1)) * Cc * HW;

        #pragma unroll
        for (int d = 0; d < DD; d++) {
            float D  = depth[d];
            float px = rx * D + tx;
            float py = ry * D + ty;
            float pz = rz * D + tz;
            float rpz = 1.0f / pz;
            float gx = px * rpz;
            float gy = py * rpz;

            float x0f = floorf(gx);
            float y0f = floorf(gy);
            float wx1 = gx - x0f;
            float wy1 = gy - y0f;
            float wx0 = 1.0f - wx1;
            float wy0 = 1.0f - wy1;

            // clamp patch origin
            float xbf = fminf(fmaxf(x0f, 0.0f), (float)(Ww - 2));
            float ybf = fminf(fmaxf(y0f, 0.0f), (float)(Hh - 2));
            float dxf = x0f - xbf;   // 0 interior, -1/+1 at border, else far OOB
            float dyf = y0f - ybf;

            // remap per-axis weights onto clamped patch columns/rows
            float pcx0 = (dxf == 0.0f) ? wx0 : ((dxf == -1.0f) ? wx1 : 0.0f);
            float pcx1 = (dxf == 0.0f) ? wx1 : ((dxf ==  1.0f) ? wx0 : 0.0f);
            float pcy0 = (dyf == 0.0f) ? wy0 : ((dyf == -1.0f) ? wy1 : 0.0f);
            float pcy1 = (dyf == 0.0f) ? wy1 : ((dyf ==  1.0f) ? wy0 : 0.0f);

            float W00 = pcx0 * pcy0 * scale;
            float W10 = pcx1 * pcy0 * scale;
            float W01 = pcx0 * pcy1 * scale;
            float W11 = pcx1 * pcy1 * scale;

            int o00 = (int)ybf * Ww + (int)xbf;

            #pragma unroll
            for (int c = 0; c < Cc; c++) {
                const float* p = src + (size_t)c * HW + o00;
                float val = W00 * p[0] + W10 * p[1] + W01 * p[Ww] + W11 * p[Ww + 1];
                acc[(c >> 2) * DD + d] += val * ref[c];
            }
        }
    }

    float dn = 1.0f / (wsum + 1e-6f);
    float* so = sim_out + (size_t)b * (GG * DD) * HW + pix;
    #pragma unroll
    for (int k = 0; k < GG * DD; k++) so[(size_t)k * HW] = acc[k] * dn;
}

extern "C" void kernel_launch(void* const* d_in, const int* in_sizes, int n_in,
                              void* d_out, int out_size, void* d_ws, size_t ws_size,
                              hipStream_t stream) {
    const float* depth_values   = (const float*)d_in[0];
    const float* features       = (const float*)d_in[1];
    const float* projm          = (const float*)d_in[2];
    const float* depth_interval = (const float*)d_in[3];
    const float* view_weights   = (const float*)d_in[6];

    float* out      = (float*)d_out;
    float* sim_out  = out;                              // (B, G*DD, H, W)
    float* samp_out = out + (size_t)Bn * GG * DD * HW;  // (B, DD, H, W)
    float* P12      = (float*)d_ws;                     // 16 x 12 floats

    proj_kernel<<<1, 64, 0, stream>>>(projm, P12);
    cost_kernel<<<(Bn * HW) / 256, 256, 0, stream>>>(
        depth_values, features, depth_interval, view_weights, P12, sim_out, samp_out);
}

// Round 3
// 528.150 us; speedup vs baseline: 1.5523x; 1.2984x over previous
//
#include <hip/hip_runtime.h>
#include <math.h>

#define Bn 4
#define Vn 5
#define Cc 32
#define Hh 256
#define Ww 320
#define DD 4
#define GG 8
#define HW (Hh*Ww)
#define BLOCKS_PER_B (HW/256)   // 320

// ---------------------------------------------------------------------------
// Prologue: per (b, src_view i=1..4) compute P = src_proj_new @ inv(ref_proj_new)
// ---------------------------------------------------------------------------
__global__ void proj_kernel(const float* __restrict__ proj, float* __restrict__ out12) {
    int t = blockIdx.x * blockDim.x + threadIdx.x;
    if (t >= Bn * (Vn - 1)) return;
    int b = t / (Vn - 1);
    int i = t % (Vn - 1) + 1;

    const float* pb = proj + (size_t)b * Vn * 2 * 16;

    double refm[16], srcm[16];
    {
        const float* E = pb + 0 * 32 + 0;
        const float* K = pb + 0 * 32 + 16;
        for (int r = 0; r < 3; r++)
            for (int c = 0; c < 4; c++) {
                double s = 0.0;
                for (int k = 0; k < 3; k++) s += (double)K[r*4+k] * (double)E[k*4+c];
                refm[r*4+c] = s;
            }
        for (int c = 0; c < 4; c++) refm[12+c] = (double)E[12+c];
    }
    {
        const float* E = pb + i * 32 + 0;
        const float* K = pb + i * 32 + 16;
        for (int r = 0; r < 3; r++)
            for (int c = 0; c < 4; c++) {
                double s = 0.0;
                for (int k = 0; k < 3; k++) s += (double)K[r*4+k] * (double)E[k*4+c];
                srcm[r*4+c] = s;
            }
        for (int c = 0; c < 4; c++) srcm[12+c] = (double)E[12+c];
    }

    double a[16], inv[16];
    for (int k = 0; k < 16; k++) { a[k] = refm[k]; inv[k] = 0.0; }
    inv[0] = inv[5] = inv[10] = inv[15] = 1.0;
    for (int col = 0; col < 4; col++) {
        int piv = col; double best = fabs(a[col*4+col]);
        for (int r = col + 1; r < 4; r++) {
            double v = fabs(a[r*4+col]);
            if (v > best) { best = v; piv = r; }
        }
        if (piv != col) {
            for (int c = 0; c < 4; c++) {
                double tmp = a[col*4+c]; a[col*4+c] = a[piv*4+c]; a[piv*4+c] = tmp;
                tmp = inv[col*4+c]; inv[col*4+c] = inv[piv*4+c]; inv[piv*4+c] = tmp;
            }
        }
        double rd = 1.0 / a[col*4+col];
        for (int c = 0; c < 4; c++) { a[col*4+c] *= rd; inv[col*4+c] *= rd; }
        for (int r = 0; r < 4; r++) {
            if (r == col) continue;
            double f = a[r*4+col];
            for (int c = 0; c < 4; c++) { a[r*4+c] -= f * a[col*4+c]; inv[r*4+c] -= f * inv[col*4+c]; }
        }
    }

    double P[16];
    for (int r = 0; r < 4; r++)
        for (int c = 0; c < 4; c++) {
            double s = 0.0;
            for (int k = 0; k < 4; k++) s += srcm[r*4+k] * inv[k*4+c];
            P[r*4+c] = s;
        }

    float* o = out12 + t * 12;
    o[0] = (float)P[0];  o[1] = (float)P[1];  o[2]  = (float)P[2];
    o[3] = (float)P[4];  o[4] = (float)P[5];  o[5]  = (float)P[6];
    o[6] = (float)P[8];  o[7] = (float)P[9];  o[8]  = (float)P[10];
    o[9] = (float)P[3];  o[10] = (float)P[7]; o[11] = (float)P[11];
}

// ---------------------------------------------------------------------------
// Main kernel: one thread per (b,h,w), channels processed in 4 chunks of 8.
//  * Live state per chunk: ref8[8] + acc[2][4] + depth[4] + vw[4] + temps
//    (~30 regs) + in-flight gathers -> fits 85-VGPR cap WITHOUT spilling
//    (round 2's ref[32]+acc[32] spilled to scratch: +630 MB HBM traffic).
//  * b is computed from blockIdx only -> wave-uniform -> P12 reads are s_loads.
//  * Bilinear: one base address per (c,d); corners are immediate-offset loads
//    (+4B/+1280B/+1284B). Border handled by clamping patch origin to
//    [0,W-2]x[0,H-2] and remapping the per-axis weights onto patch cols/rows.
// ---------------------------------------------------------------------------
__global__ __launch_bounds__(256, 6) void cost_kernel(
    const float* __restrict__ depth_values,
    const float* __restrict__ features,
    const float* __restrict__ depth_interval,
    const float* __restrict__ view_weights,
    const float* __restrict__ P12,
    float* __restrict__ sim_out,
    float* __restrict__ samp_out)
{
    int b   = blockIdx.x / BLOCKS_PER_B;                       // wave-uniform
    int pix = (blockIdx.x - b * BLOCKS_PER_B) * 256 + threadIdx.x;
    int h   = pix / Ww;
    int w   = pix - h * Ww;

    float inv_d = 1.0f / depth_values[b * HW + pix];
    float itv   = depth_interval[b * HW + pix];
    float dmin  = inv_d - 2.0f * itv;
    float step  = (4.0f * itv) / 3.0f;

    float depth[DD];
    #pragma unroll
    for (int d = 0; d < DD; d++) {
        float s  = dmin + (float)d * step;
        depth[d] = 1.0f / s;
        samp_out[((size_t)b * DD + d) * HW + pix] = depth[d];
    }

    float vw[Vn - 1];
    float wsum = 0.0f;
    #pragma unroll
    for (int i = 0; i < Vn - 1; i++) {
        vw[i] = view_weights[((size_t)b * (Vn - 1) + i) * HW + pix];
        wsum += vw[i];
    }
    float dn = 1.0f / (wsum + 1e-6f);

    const float xf = (float)w, yf = (float)h;
    const float* refp = features + (size_t)b * Vn * Cc * HW + pix;
    float* so_base = sim_out + (size_t)b * (GG * DD) * HW + pix;

    #pragma unroll 1
    for (int c0 = 0; c0 < Cc; c0 += 8) {
        float ref8[8];
        #pragma unroll
        for (int j = 0; j < 8; j++) ref8[j] = refp[(size_t)(c0 + j) * HW];

        float acc[2][DD];
        #pragma unroll
        for (int g2 = 0; g2 < 2; g2++)
            #pragma unroll
            for (int d = 0; d < DD; d++) acc[g2][d] = 0.0f;

        #pragma unroll 1
        for (int i = 0; i < Vn - 1; i++) {
            const float* P = P12 + (b * (Vn - 1) + i) * 12;   // uniform -> s_load
            float rx = P[0] * xf + P[1] * yf + P[2];
            float ry = P[3] * xf + P[4] * yf + P[5];
            float rz = P[6] * xf + P[7] * yf + P[8];
            float tx = P[9], ty = P[10], tz = P[11];

            float scale = 0.25f * vw[i];
            const float* src = features + ((size_t)(b * Vn) + (i + 1)) * Cc * HW
                             + (size_t)c0 * HW;

            #pragma unroll
            for (int d = 0; d < DD; d++) {
                float D  = depth[d];
                float px = rx * D + tx;
                float py = ry * D + ty;
                float pz = rz * D + tz;
                float rpz = 1.0f / pz;
                float gx = px * rpz;
                float gy = py * rpz;

                float x0f = floorf(gx);
                float y0f = floorf(gy);
                float wx1 = gx - x0f;
                float wy1 = gy - y0f;
                float wx0 = 1.0f - wx1;
                float wy0 = 1.0f - wy1;

                float xbf = fminf(fmaxf(x0f, 0.0f), (float)(Ww - 2));
                float ybf = fminf(fmaxf(y0f, 0.0f), (float)(Hh - 2));
                float dxf = x0f - xbf;
                float dyf = y0f - ybf;

                float pcx0 = (dxf == 0.0f) ? wx0 : ((dxf == -1.0f) ? wx1 : 0.0f);
                float pcx1 = (dxf == 0.0f) ? wx1 : ((dxf ==  1.0f) ? wx0 : 0.0f);
                float pcy0 = (dyf == 0.0f) ? wy0 : ((dyf == -1.0f) ? wy1 : 0.0f);
                float pcy1 = (dyf == 0.0f) ? wy1 : ((dyf ==  1.0f) ? wy0 : 0.0f);

                float W00 = pcx0 * pcy0 * scale;
                float W10 = pcx1 * pcy0 * scale;
                float W01 = pcx0 * pcy1 * scale;
                float W11 = pcx1 * pcy1 * scale;

                int o00 = (int)ybf * Ww + (int)xbf;

                #pragma unroll
                for (int j = 0; j < 8; j++) {
                    const float* p = src + (size_t)j * HW + o00;
                    float val = W00 * p[0] + W10 * p[1] + W01 * p[Ww] + W11 * p[Ww + 1];
                    acc[j >> 2][d] += val * ref8[j];
                }
            }
        }

        // similarity index k = g*DD + d, g = c0/4 + g2
        #pragma unroll
        for (int g2 = 0; g2 < 2; g2++)
            #pragma unroll
            for (int d = 0; d < DD; d++)
                so_base[(size_t)(((c0 >> 2) + g2) * DD + d) * HW] = acc[g2][d] * dn;
    }
}

extern "C" void kernel_launch(void* const* d_in, const int* in_sizes, int n_in,
                              void* d_out, int out_size, void* d_ws, size_t ws_size,
                              hipStream_t stream) {
    const float* depth_values   = (const float*)d_in[0];
    const float* features       = (const float*)d_in[1];
    const float* projm          = (const float*)d_in[2];
    const float* depth_interval = (const float*)d_in[3];
    const float* view_weights   = (const float*)d_in[6];

    float* out      = (float*)d_out;
    float* sim_out  = out;                              // (B, G*DD, H, W)
    float* samp_out = out + (size_t)Bn * GG * DD * HW;  // (B, DD, H, W)
    float* P12      = (float*)d_ws;                     // 16 x 12 floats

    proj_kernel<<<1, 64, 0, stream>>>(projm, P12);
    cost_kernel<<<Bn * BLOCKS_PER_B, 256, 0, stream>>>(
        depth_values, features, depth_interval, view_weights, P12, sim_out, samp_out);
}